// Round 12
// baseline (132.959 us; speedup 1.0000x reference)
//
#include <hip/hip_runtime.h>
#include <math.h>

#define N_Q   4096
#define N_DB  65536
#define DIM   32
#define KNN   5
#define NC    64                 // chunks
#define CH    (N_DB / NC)        // 1024 points per chunk
#define NSUB  32                 // 32-point subtiles per chunk
#define NCAND (NC * 6)           // 384 candidates per query
#define BIAS  256.0f

typedef _Float16 half8  __attribute__((ext_vector_type(8)));
typedef __fp16   fp16x2 __attribute__((ext_vector_type(2)));
typedef float floatx16  __attribute__((ext_vector_type(16)));

union H8  { half8 h; uint4 u4; unsigned u[4]; };
union F16 { floatx16 v; float4 q4[4]; unsigned w[16]; };
union HU  { fp16x2 h2; unsigned u; };

__device__ __forceinline__ unsigned cvt2(float a, float b) {
    HU t; t.h2 = __builtin_amdgcn_cvt_pkrtz(a, b);
    return t.u;
}

// opaque asm loads (T4 pattern): loads stay in flight across compute phases,
// gated only by our counted s_waitcnt.
__device__ __forceinline__ void gl4(uint4& d, unsigned long long a) {
    asm volatile("global_load_dwordx4 %0, %1, off" : "=v"(d) : "v"(a) : "memory");
}
__device__ __forceinline__ void gl4_1024(uint4& d, unsigned long long a) {
    asm volatile("global_load_dwordx4 %0, %1, off offset:1024" : "=v"(d) : "v"(a) : "memory");
}
__device__ __forceinline__ void gl1(unsigned& d, unsigned long long a) {
    asm volatile("global_load_dword %0, %1, off" : "=v"(d) : "v"(a) : "memory");
}
// depth-1 ping-pong: at the wait, the other slot's 3 loads are in flight.
// trailing sched_barrier keeps consumers below the wait (rule #18).
#define VMWAIT3 do { asm volatile("s_waitcnt vmcnt(3)" ::: "memory"); \
                     __builtin_amdgcn_sched_barrier(0); } while (0)

// ---------------- kernel 0: fp32 db -> tile-major fp16 image + packed biased norm ----------------
// DBh: [tile=p>>5][kgroup 0..3][row=p&31][8 halves]  (2 KB per 32-pt tile)
// DBn: [p] one dword = fp16 pair (hi, lo), hi+lo ~= BIAS - 0.5*|db|^2
__global__ __launch_bounds__(256) void k_prep(const float* __restrict__ DB,
                                              uint4* __restrict__ DBh,
                                              unsigned* __restrict__ DBn) {
    int p = blockIdx.x * 256 + threadIdx.x;
    const float4* src = (const float4*)(DB + (size_t)p * DIM);
    float4 f[8]; float s = 0.f;
#pragma unroll
    for (int j = 0; j < 8; ++j) {
        f[j] = src[j];
        s += f[j].x * f[j].x + f[j].y * f[j].y + f[j].z * f[j].z + f[j].w * f[j].w;
    }
    float v  = BIAS - 0.5f * s;
    float hi = (float)(__fp16)v;      // fp16-representable head
    float lo = v - hi;                // exact residual
    DBn[p] = cvt2(hi, lo);            // k0 = hi (low half), k1 = lo
    int t = p >> 5, r = p & 31;
#pragma unroll
    for (int gi = 0; gi < 4; ++gi) {
        uint4 g;
        g.x = cvt2(f[2 * gi].x, f[2 * gi].y);
        g.y = cvt2(f[2 * gi].z, f[2 * gi].w);
        g.z = cvt2(f[2 * gi + 1].x, f[2 * gi + 1].y);
        g.w = cvt2(f[2 * gi + 1].z, f[2 * gi + 1].w);
        DBh[(size_t)t * 128 + gi * 32 + r] = g;
    }
}

// ---------------- kernel 1: MFMA scan; tournament+merge as ONE asm blob ----------------
// (R5 verified state — last green. The full-asm K-loop rewrite (R6-R11) never
// passed numerics and is abandoned; without disasm access the residual bug is
// not localizable. This version: builtin MFMAs + 52-op asm tournament blob.)
__global__ __launch_bounds__(256, 4) void k_scan(const float* __restrict__ Q,
                                                 const uint4* __restrict__ DBh,
                                                 const unsigned* __restrict__ DBn,
                                                 unsigned* __restrict__ cand) {
    const int tid = threadIdx.x, lane = tid & 63, w = tid >> 6;   // w=0..3
    const int h = lane >> 5, row = lane & 31;
    const int chunk = blockIdx.x & (NC - 1);   // same-chunk blocks: stride 64 -> same XCD
    const int qb    = blockIdx.x >> 6;         // 0..31
    const int q     = qb * 128 + w * 32 + row;
    const int pbase = chunk * CH;

    // B-frags: convert this lane's query dims once
    const float* qp = Q + (size_t)q * DIM;
    float4 qa = *(const float4*)(qp + h * 8);
    float4 qb4 = *(const float4*)(qp + h * 8 + 4);
    float4 qc = *(const float4*)(qp + 16 + h * 8);
    float4 qd = *(const float4*)(qp + 16 + h * 8 + 4);
    H8 b1, b2, b3;
    b1.u[0] = cvt2(qa.x, qa.y);   b1.u[1] = cvt2(qa.z, qa.w);
    b1.u[2] = cvt2(qb4.x, qb4.y); b1.u[3] = cvt2(qb4.z, qb4.w);
    b2.u[0] = cvt2(qc.x, qc.y);   b2.u[1] = cvt2(qc.z, qc.w);
    b2.u[2] = cvt2(qd.x, qd.y);   b2.u[3] = cvt2(qd.z, qd.w);
    b3.u[0] = (h == 0) ? cvt2(1.f, 1.f) : 0u;   // k0,k1 = 1 for the norm MFMA
    b3.u[1] = 0u; b3.u[2] = 0u; b3.u[3] = 0u;
    const unsigned hmask = (h == 0) ? 0xFFFFFFFFu : 0u;

    // opaque VGPR mask -> pack is a single v_and_or_b32 (S2 = uniform SGPR id)
    unsigned maskv;
    asm("v_mov_b32 %0, 0xFFFFFC00" : "=v"(maskv));

    // per-lane byte addresses: tile (chunk*32+s), kgroup h (a1) / 2+h (a2), row
    const unsigned long long abase_u =
        (unsigned long long)(DBh + (size_t)(pbase >> 5) * 128 + h * 32 + row);
    const unsigned long long nbase_u =
        (unsigned long long)(DBn + pbase + row);

    floatx16 zc;                       // constant zero C (fine if parked in AGPRs)
#pragma unroll
    for (int r = 0; r < 16; ++r) zc[r] = 0.f;

    float tk[6];
#pragma unroll
    for (int r = 0; r < 6; ++r) tk[r] = 0.f;

    constexpr int ROWC[16] = {0,1,2,3, 8,9,10,11, 16,17,18,19, 24,25,26,27}; // bit 2 free (=h)

    auto compute = [&](const H8& A1, const H8& A2, unsigned A3u, const int s) {
        H8 a3;
        a3.u[0] = A3u & hmask;         // only h=0 lanes carry (hi,lo)
        a3.u[1] = 0u; a3.u[2] = 0u; a3.u[3] = 0u;
        floatx16 acc = __builtin_amdgcn_mfma_f32_32x32x16_f16(a3.h, b3.h, zc, 0, 0, 0);
        acc = __builtin_amdgcn_mfma_f32_32x32x16_f16(A1.h, b1.h, acc, 0, 0, 0);
        acc = __builtin_amdgcn_mfma_f32_32x32x16_f16(A2.h, b2.h, acc, 0, 0, 0);
        // pack 10-bit chunk-local id; integer ops, uniform (meta|ROWC) folds to SGPR
        F16 pk; pk.v = acc;
        const unsigned meta = (unsigned)(s << 5);
        unsigned p[16];
#pragma unroll
        for (int r = 0; r < 16; ++r)
            p[r] = (pk.w[r] & maskv) | (meta | (unsigned)ROWC[r]);
        // top-2-of-16 + merge into sorted tk[6]: 52 instructions, op-identical to
        // the fminf/fmaxf version, as one asm blob (no canonicalize, no AGPR churn)
        float q0, q1, q2, q3, T0, T1, T2, T3, U0, U1, U2, U3;
        asm(// quad 0: (T0,U0) = top2 of p0..p3
            "v_max_f32 %[q0], %[p0], %[p1]\n\t"
            "v_min_f32 %[q1], %[p0], %[p1]\n\t"
            "v_max_f32 %[q2], %[p2], %[p3]\n\t"
            "v_min_f32 %[q3], %[p2], %[p3]\n\t"
            "v_max_f32 %[T0], %[q0], %[q2]\n\t"
            "v_min_f32 %[U0], %[q0], %[q2]\n\t"
            "v_max3_f32 %[U0], %[q1], %[q3], %[U0]\n\t"
            // quad 1
            "v_max_f32 %[q0], %[p4], %[p5]\n\t"
            "v_min_f32 %[q1], %[p4], %[p5]\n\t"
            "v_max_f32 %[q2], %[p6], %[p7]\n\t"
            "v_min_f32 %[q3], %[p6], %[p7]\n\t"
            "v_max_f32 %[T1], %[q0], %[q2]\n\t"
            "v_min_f32 %[U1], %[q0], %[q2]\n\t"
            "v_max3_f32 %[U1], %[q1], %[q3], %[U1]\n\t"
            // quad 2
            "v_max_f32 %[q0], %[p8], %[p9]\n\t"
            "v_min_f32 %[q1], %[p8], %[p9]\n\t"
            "v_max_f32 %[q2], %[p10], %[p11]\n\t"
            "v_min_f32 %[q3], %[p10], %[p11]\n\t"
            "v_max_f32 %[T2], %[q0], %[q2]\n\t"
            "v_min_f32 %[U2], %[q0], %[q2]\n\t"
            "v_max3_f32 %[U2], %[q1], %[q3], %[U2]\n\t"
            // quad 3
            "v_max_f32 %[q0], %[p12], %[p13]\n\t"
            "v_min_f32 %[q1], %[p12], %[p13]\n\t"
            "v_max_f32 %[q2], %[p14], %[p15]\n\t"
            "v_min_f32 %[q3], %[p14], %[p15]\n\t"
            "v_max_f32 %[T3], %[q0], %[q2]\n\t"
            "v_min_f32 %[U3], %[q0], %[q2]\n\t"
            "v_max3_f32 %[U3], %[q1], %[q3], %[U3]\n\t"
            // combine quads: c1 -> T1, c2 -> T3
            "v_max_f32 %[q0], %[T0], %[T1]\n\t"
            "v_min_f32 %[q1], %[T0], %[T1]\n\t"
            "v_max3_f32 %[q2], %[U0], %[U1], %[q1]\n\t"
            "v_max_f32 %[q1], %[T2], %[T3]\n\t"
            "v_min_f32 %[q3], %[T2], %[T3]\n\t"
            "v_max3_f32 %[T0], %[U2], %[U3], %[q3]\n\t"
            "v_max_f32 %[T1], %[q0], %[q1]\n\t"
            "v_min_f32 %[T2], %[q0], %[q1]\n\t"
            "v_max3_f32 %[T3], %[q2], %[T0], %[T2]\n\t"
            // merge sorted pair (c1=T1 >= c2=T3) into sorted tk[6] (merge-path)
            "v_min_f32 %[q0], %[tk0], %[T1]\n\t"
            "v_min_f32 %[q1], %[tk1], %[T1]\n\t"
            "v_min_f32 %[q2], %[tk2], %[T1]\n\t"
            "v_min_f32 %[q3], %[tk3], %[T1]\n\t"
            "v_min_f32 %[U0], %[tk4], %[T1]\n\t"
            "v_min_f32 %[U1], %[tk0], %[T3]\n\t"
            "v_min_f32 %[U2], %[tk1], %[T3]\n\t"
            "v_min_f32 %[U3], %[tk2], %[T3]\n\t"
            "v_min_f32 %[T0], %[tk3], %[T3]\n\t"
            "v_max_f32 %[tk0], %[tk0], %[T1]\n\t"
            "v_max3_f32 %[tk1], %[tk1], %[q0], %[T3]\n\t"
            "v_max3_f32 %[tk2], %[tk2], %[q1], %[U1]\n\t"
            "v_max3_f32 %[tk3], %[tk3], %[q2], %[U2]\n\t"
            "v_max3_f32 %[tk4], %[tk4], %[q3], %[U3]\n\t"
            "v_max3_f32 %[tk5], %[tk5], %[U0], %[T0]"
            : [tk0]"+v"(tk[0]), [tk1]"+v"(tk[1]), [tk2]"+v"(tk[2]),
              [tk3]"+v"(tk[3]), [tk4]"+v"(tk[4]), [tk5]"+v"(tk[5]),
              [q0]"=&v"(q0), [q1]"=&v"(q1), [q2]"=&v"(q2), [q3]"=&v"(q3),
              [T0]"=&v"(T0), [T1]"=&v"(T1), [T2]"=&v"(T2), [T3]"=&v"(T3),
              [U0]"=&v"(U0), [U1]"=&v"(U1), [U2]"=&v"(U2), [U3]"=&v"(U3)
            : [p0]"v"(p[0]),  [p1]"v"(p[1]),  [p2]"v"(p[2]),  [p3]"v"(p[3]),
              [p4]"v"(p[4]),  [p5]"v"(p[5]),  [p6]"v"(p[6]),  [p7]"v"(p[7]),
              [p8]"v"(p[8]),  [p9]"v"(p[9]),  [p10]"v"(p[10]), [p11]"v"(p[11]),
              [p12]"v"(p[12]), [p13]"v"(p[13]), [p14]"v"(p[14]), [p15]"v"(p[15]));
    };

    auto LD = [&](H8& x1, H8& x2, unsigned& x3, const int s) {
        const unsigned long long a = abase_u + (unsigned long long)s * 2048ull;
        gl4(x1.u4, a);                 // kgroup h
        gl4_1024(x2.u4, a);            // kgroup 2+h  (+1024 B)
        gl1(x3, nbase_u + (unsigned long long)s * 128ull);
    };

    // depth-1 ping-pong, 2 slots (tail load runs <=2KB past the chunk --
    // still inside workspace, unused)
    H8 sA1, sA2, sB1, sB2;
    unsigned nA, nB;
    LD(sA1, sA2, nA, 0);
    for (int s = 0; s < NSUB; s += 2) {
        LD(sB1, sB2, nB, s + 1);
        VMWAIT3; compute(sA1, sA2, nA, s);
        LD(sA1, sA2, nA, s + 2);
        VMWAIT3; compute(sB1, sB2, nB, s + 1);
    }

    // set the h bit (bit 2 of id field) on the 6 survivors, once per chunk
#pragma unroll
    for (int r = 0; r < 6; ++r)
        tk[r] = __uint_as_float(__float_as_uint(tk[r]) | (unsigned)(h << 2));

    // cross-half merge: SNAPSHOT partner's list before mutating
    float other[6];
#pragma unroll
    for (int i = 0; i < 6; ++i) other[i] = __shfl_xor(tk[i], 32, 64);
#pragma unroll
    for (int i = 0; i < 6; ++i) {
        float val = other[i];
#pragma unroll
        for (int j = 0; j < 6; ++j) { float mx = fmaxf(tk[j], val); val = fminf(tk[j], val); tk[j] = mx; }
    }
    if (h == 0) {
        unsigned* dst = cand + ((size_t)q * NC + chunk) * 6;
#pragma unroll
        for (int r = 0; r < 6; ++r) dst[r] = __float_as_uint(tk[r]);
    }
}

// ---------------- kernel 2: global approx top-12, exact rescore, top-5, blend ----------------
__global__ __launch_bounds__(256) void k_merge(const float* __restrict__ Q,
                                               const float* __restrict__ DB,
                                               const float* __restrict__ AUX,
                                               const unsigned* __restrict__ cand,
                                               float* __restrict__ out) {
    const int tid = threadIdx.x, lane = tid & 63, w = tid >> 6;
    const int q = blockIdx.x * 4 + w;

    const unsigned* cq = cand + (size_t)q * NCAND + (size_t)lane * 6;
    float cur[6];
#pragma unroll
    for (int r = 0; r < 6; ++r) cur[r] = __uint_as_float(cq[r]);

    float wv[12]; int wl[12];
#pragma unroll
    for (int r = 0; r < 12; ++r) {
        float bv = cur[0]; int bl = lane;
#pragma unroll
        for (int off = 32; off >= 1; off >>= 1) {
            float ov = __shfl_xor(bv, off, 64);
            int   ol = __shfl_xor(bl, off, 64);
            if (ov > bv || (ov == bv && ol < bl)) { bv = ov; bl = ol; }
        }
        wv[r] = bv; wl[r] = bl;
        if (bl == lane) {
#pragma unroll
            for (int s = 0; s < 5; ++s) cur[s] = cur[s + 1];
            cur[5] = -1.f;
        }
    }

    float dist = 1e30f; int dbi = 0x7fffffff;
    if (lane < 12) {
        unsigned u = __float_as_uint(wv[lane]) & 1023u;   // chunk-local point id
        dbi = wl[lane] * CH + (int)u;
        const float4* dp = (const float4*)(DB + (size_t)dbi * DIM);
        const float4* qp = (const float4*)(Q + (size_t)q * DIM);
        float dot = 0.f, qs = 0.f, ds = 0.f;
#pragma unroll
        for (int j = 0; j < DIM / 4; ++j) {
            float4 a = qp[j], d = dp[j];
            dot += a.x * d.x + a.y * d.y + a.z * d.z + a.w * d.w;
            qs  += a.x * a.x + a.y * a.y + a.z * a.z + a.w * a.w;
            ds  += d.x * d.x + d.y * d.y + d.z * d.z + d.w * d.w;
        }
        dist = sqrtf(fmaxf(qs + ds - 2.f * dot, 0.f));
    }
    float wd[KNN]; int wi[KNN];
#pragma unroll
    for (int r = 0; r < KNN; ++r) {
        float bd = dist; int bi = dbi;
#pragma unroll
        for (int off = 32; off >= 1; off >>= 1) {
            float od = __shfl_xor(bd, off, 64);
            int   oi = __shfl_xor(bi, off, 64);
            if (od < bd || (od == bd && oi < bi)) { bd = od; bi = oi; }
        }
        wd[r] = bd; wi[r] = bi;
        if (dist == bd && dbi == bi) dist = 1e30f;
    }
    float ww[KNN], W = 0.f;
#pragma unroll
    for (int r = 0; r < KNN; ++r) { ww[r] = 1.f / (wd[r] + 1e-6f); W += ww[r]; }
    if (lane < DIM) {
        float o = 0.f;
#pragma unroll
        for (int r = 0; r < KNN; ++r) o += ww[r] * AUX[(size_t)wi[r] * DIM + lane];
        out[(size_t)q * DIM + lane] = o / W;
    }
}

// ---------------- launch ----------------
extern "C" void kernel_launch(void* const* d_in, const int* in_sizes, int n_in,
                              void* d_out, int out_size, void* d_ws, size_t ws_size,
                              hipStream_t stream) {
    const float* Q   = (const float*)d_in[0];
    const float* DB  = (const float*)d_in[1];
    const float* AUX = (const float*)d_in[2];
    float* out = (float*)d_out;

    char* ws = (char*)d_ws;
    uint4*    DBh = (uint4*)ws;                         ws += (size_t)(N_DB / 32) * 128 * 16; // 4 MB
    unsigned* DBn = (unsigned*)ws;                      ws += (size_t)N_DB * 4;               // 256 KB
    unsigned* cand = (unsigned*)ws;                     // 4096*384*4 = 6 MB  (total 10.25 MB)

    k_prep<<<N_DB / 256, 256, 0, stream>>>(DB, DBh, DBn);
    k_scan<<<(N_Q / 128) * NC, 256, 0, stream>>>(Q, DBh, DBn, cand);
    k_merge<<<N_Q / 4, 256, 0, stream>>>(Q, DB, AUX, cand, out);
}

// Round 13
// 132.353 us; speedup vs baseline: 1.0046x; 1.0046x over previous
//
#include <hip/hip_runtime.h>
#include <math.h>

#define N_Q   4096
#define N_DB  65536
#define DIM   32
#define KNN   5
#define NC    64                 // chunks
#define CH    (N_DB / NC)        // 1024 points per chunk
#define NSUB  32                 // 32-point subtiles per chunk
#define NCAND (NC * 6)           // 384 candidates per query
#define BIAS  256.0f

typedef _Float16 half8  __attribute__((ext_vector_type(8)));
typedef __fp16   fp16x2 __attribute__((ext_vector_type(2)));
typedef float floatx16  __attribute__((ext_vector_type(16)));

union H8  { half8 h; uint4 u4; unsigned u[4]; };
union F16 { floatx16 v; float4 q4[4]; unsigned w[16]; };
union HU  { fp16x2 h2; unsigned u; };

__device__ __forceinline__ unsigned cvt2(float a, float b) {
    HU t; t.h2 = __builtin_amdgcn_cvt_pkrtz(a, b);
    return t.u;
}

// opaque asm loads (T4 pattern): loads stay in flight across compute phases,
// gated only by our counted s_waitcnt.
__device__ __forceinline__ void gl4(uint4& d, unsigned long long a) {
    asm volatile("global_load_dwordx4 %0, %1, off" : "=v"(d) : "v"(a) : "memory");
}
__device__ __forceinline__ void gl4_1024(uint4& d, unsigned long long a) {
    asm volatile("global_load_dwordx4 %0, %1, off offset:1024" : "=v"(d) : "v"(a) : "memory");
}
__device__ __forceinline__ void gl1(unsigned& d, unsigned long long a) {
    asm volatile("global_load_dword %0, %1, off" : "=v"(d) : "v"(a) : "memory");
}
// depth-1 ping-pong: at the wait, the other slot's 3 loads are in flight.
// trailing sched_barrier keeps consumers below the wait (rule #18).
#define VMWAIT3 do { asm volatile("s_waitcnt vmcnt(3)" ::: "memory"); \
                     __builtin_amdgcn_sched_barrier(0); } while (0)

// ---------------- kernel 0: fp32 db -> tile-major fp16 image + packed biased norm ----------------
// DBh: [tile=p>>5][kgroup 0..3][row=p&31][8 halves]  (2 KB per 32-pt tile)
// DBn: [p] one dword = fp16 pair (hi, lo), hi+lo ~= BIAS - 0.5*|db|^2
__global__ __launch_bounds__(256) void k_prep(const float* __restrict__ DB,
                                              uint4* __restrict__ DBh,
                                              unsigned* __restrict__ DBn) {
    int p = blockIdx.x * 256 + threadIdx.x;
    const float4* src = (const float4*)(DB + (size_t)p * DIM);
    float4 f[8]; float s = 0.f;
#pragma unroll
    for (int j = 0; j < 8; ++j) {
        f[j] = src[j];
        s += f[j].x * f[j].x + f[j].y * f[j].y + f[j].z * f[j].z + f[j].w * f[j].w;
    }
    float v  = BIAS - 0.5f * s;
    float hi = (float)(__fp16)v;      // fp16-representable head
    float lo = v - hi;                // exact residual
    DBn[p] = cvt2(hi, lo);            // k0 = hi (low half), k1 = lo
    int t = p >> 5, r = p & 31;
#pragma unroll
    for (int gi = 0; gi < 4; ++gi) {
        uint4 g;
        g.x = cvt2(f[2 * gi].x, f[2 * gi].y);
        g.y = cvt2(f[2 * gi].z, f[2 * gi].w);
        g.z = cvt2(f[2 * gi + 1].x, f[2 * gi + 1].y);
        g.w = cvt2(f[2 * gi + 1].z, f[2 * gi + 1].w);
        DBh[(size_t)t * 128 + gi * 32 + r] = g;
    }
}

// ---------------- kernel 1: MFMA scan; tournament+merge as ONE asm blob ----------------
// R12 structure (verified green). Single-variable experiment this round:
// launch_bounds (256,4) -> (256,5). R12 counters: MfmaUtil arithmetic closes
// at per-SIMD 17%; VALUBusy 67% with ~4 waves/SIMD (Occupancy 47%, capped by
// the 128-reg combined V+A budget). The VALU pipe is 33% idle on latency; a
// 102-reg budget (5 blocks/CU) may now fit since the tournament live set
// moved into the asm blob (unlike R1-R4's fat C++ live set).
__global__ __launch_bounds__(256, 5) void k_scan(const float* __restrict__ Q,
                                                 const uint4* __restrict__ DBh,
                                                 const unsigned* __restrict__ DBn,
                                                 unsigned* __restrict__ cand) {
    const int tid = threadIdx.x, lane = tid & 63, w = tid >> 6;   // w=0..3
    const int h = lane >> 5, row = lane & 31;
    const int chunk = blockIdx.x & (NC - 1);   // same-chunk blocks: stride 64 -> same XCD
    const int qb    = blockIdx.x >> 6;         // 0..31
    const int q     = qb * 128 + w * 32 + row;
    const int pbase = chunk * CH;

    // B-frags: convert this lane's query dims once
    const float* qp = Q + (size_t)q * DIM;
    float4 qa = *(const float4*)(qp + h * 8);
    float4 qb4 = *(const float4*)(qp + h * 8 + 4);
    float4 qc = *(const float4*)(qp + 16 + h * 8);
    float4 qd = *(const float4*)(qp + 16 + h * 8 + 4);
    H8 b1, b2, b3;
    b1.u[0] = cvt2(qa.x, qa.y);   b1.u[1] = cvt2(qa.z, qa.w);
    b1.u[2] = cvt2(qb4.x, qb4.y); b1.u[3] = cvt2(qb4.z, qb4.w);
    b2.u[0] = cvt2(qc.x, qc.y);   b2.u[1] = cvt2(qc.z, qc.w);
    b2.u[2] = cvt2(qd.x, qd.y);   b2.u[3] = cvt2(qd.z, qd.w);
    b3.u[0] = (h == 0) ? cvt2(1.f, 1.f) : 0u;   // k0,k1 = 1 for the norm MFMA
    b3.u[1] = 0u; b3.u[2] = 0u; b3.u[3] = 0u;
    const unsigned hmask = (h == 0) ? 0xFFFFFFFFu : 0u;

    // opaque VGPR mask -> pack is a single v_and_or_b32 (S2 = uniform SGPR id)
    unsigned maskv;
    asm("v_mov_b32 %0, 0xFFFFFC00" : "=v"(maskv));

    // per-lane byte addresses: tile (chunk*32+s), kgroup h (a1) / 2+h (a2), row
    const unsigned long long abase_u =
        (unsigned long long)(DBh + (size_t)(pbase >> 5) * 128 + h * 32 + row);
    const unsigned long long nbase_u =
        (unsigned long long)(DBn + pbase + row);

    floatx16 zc;                       // constant zero C (fine if parked in AGPRs)
#pragma unroll
    for (int r = 0; r < 16; ++r) zc[r] = 0.f;

    float tk[6];
#pragma unroll
    for (int r = 0; r < 6; ++r) tk[r] = 0.f;

    constexpr int ROWC[16] = {0,1,2,3, 8,9,10,11, 16,17,18,19, 24,25,26,27}; // bit 2 free (=h)

    auto compute = [&](const H8& A1, const H8& A2, unsigned A3u, const int s) {
        H8 a3;
        a3.u[0] = A3u & hmask;         // only h=0 lanes carry (hi,lo)
        a3.u[1] = 0u; a3.u[2] = 0u; a3.u[3] = 0u;
        floatx16 acc = __builtin_amdgcn_mfma_f32_32x32x16_f16(a3.h, b3.h, zc, 0, 0, 0);
        acc = __builtin_amdgcn_mfma_f32_32x32x16_f16(A1.h, b1.h, acc, 0, 0, 0);
        acc = __builtin_amdgcn_mfma_f32_32x32x16_f16(A2.h, b2.h, acc, 0, 0, 0);
        // pack 10-bit chunk-local id; integer ops, uniform (meta|ROWC) folds to SGPR
        F16 pk; pk.v = acc;
        const unsigned meta = (unsigned)(s << 5);
        unsigned p[16];
#pragma unroll
        for (int r = 0; r < 16; ++r)
            p[r] = (pk.w[r] & maskv) | (meta | (unsigned)ROWC[r]);
        // top-2-of-16 + merge into sorted tk[6]: 52 instructions, op-identical to
        // the fminf/fmaxf version, as one asm blob (no canonicalize, no AGPR churn)
        float q0, q1, q2, q3, T0, T1, T2, T3, U0, U1, U2, U3;
        asm(// quad 0: (T0,U0) = top2 of p0..p3
            "v_max_f32 %[q0], %[p0], %[p1]\n\t"
            "v_min_f32 %[q1], %[p0], %[p1]\n\t"
            "v_max_f32 %[q2], %[p2], %[p3]\n\t"
            "v_min_f32 %[q3], %[p2], %[p3]\n\t"
            "v_max_f32 %[T0], %[q0], %[q2]\n\t"
            "v_min_f32 %[U0], %[q0], %[q2]\n\t"
            "v_max3_f32 %[U0], %[q1], %[q3], %[U0]\n\t"
            // quad 1
            "v_max_f32 %[q0], %[p4], %[p5]\n\t"
            "v_min_f32 %[q1], %[p4], %[p5]\n\t"
            "v_max_f32 %[q2], %[p6], %[p7]\n\t"
            "v_min_f32 %[q3], %[p6], %[p7]\n\t"
            "v_max_f32 %[T1], %[q0], %[q2]\n\t"
            "v_min_f32 %[U1], %[q0], %[q2]\n\t"
            "v_max3_f32 %[U1], %[q1], %[q3], %[U1]\n\t"
            // quad 2
            "v_max_f32 %[q0], %[p8], %[p9]\n\t"
            "v_min_f32 %[q1], %[p8], %[p9]\n\t"
            "v_max_f32 %[q2], %[p10], %[p11]\n\t"
            "v_min_f32 %[q3], %[p10], %[p11]\n\t"
            "v_max_f32 %[T2], %[q0], %[q2]\n\t"
            "v_min_f32 %[U2], %[q0], %[q2]\n\t"
            "v_max3_f32 %[U2], %[q1], %[q3], %[U2]\n\t"
            // quad 3
            "v_max_f32 %[q0], %[p12], %[p13]\n\t"
            "v_min_f32 %[q1], %[p12], %[p13]\n\t"
            "v_max_f32 %[q2], %[p14], %[p15]\n\t"
            "v_min_f32 %[q3], %[p14], %[p15]\n\t"
            "v_max_f32 %[T3], %[q0], %[q2]\n\t"
            "v_min_f32 %[U3], %[q0], %[q2]\n\t"
            "v_max3_f32 %[U3], %[q1], %[q3], %[U3]\n\t"
            // combine quads: c1 -> T1, c2 -> T3
            "v_max_f32 %[q0], %[T0], %[T1]\n\t"
            "v_min_f32 %[q1], %[T0], %[T1]\n\t"
            "v_max3_f32 %[q2], %[U0], %[U1], %[q1]\n\t"
            "v_max_f32 %[q1], %[T2], %[T3]\n\t"
            "v_min_f32 %[q3], %[T2], %[T3]\n\t"
            "v_max3_f32 %[T0], %[U2], %[U3], %[q3]\n\t"
            "v_max_f32 %[T1], %[q0], %[q1]\n\t"
            "v_min_f32 %[T2], %[q0], %[q1]\n\t"
            "v_max3_f32 %[T3], %[q2], %[T0], %[T2]\n\t"
            // merge sorted pair (c1=T1 >= c2=T3) into sorted tk[6] (merge-path)
            "v_min_f32 %[q0], %[tk0], %[T1]\n\t"
            "v_min_f32 %[q1], %[tk1], %[T1]\n\t"
            "v_min_f32 %[q2], %[tk2], %[T1]\n\t"
            "v_min_f32 %[q3], %[tk3], %[T1]\n\t"
            "v_min_f32 %[U0], %[tk4], %[T1]\n\t"
            "v_min_f32 %[U1], %[tk0], %[T3]\n\t"
            "v_min_f32 %[U2], %[tk1], %[T3]\n\t"
            "v_min_f32 %[U3], %[tk2], %[T3]\n\t"
            "v_min_f32 %[T0], %[tk3], %[T3]\n\t"
            "v_max_f32 %[tk0], %[tk0], %[T1]\n\t"
            "v_max3_f32 %[tk1], %[tk1], %[q0], %[T3]\n\t"
            "v_max3_f32 %[tk2], %[tk2], %[q1], %[U1]\n\t"
            "v_max3_f32 %[tk3], %[tk3], %[q2], %[U2]\n\t"
            "v_max3_f32 %[tk4], %[tk4], %[q3], %[U3]\n\t"
            "v_max3_f32 %[tk5], %[tk5], %[U0], %[T0]"
            : [tk0]"+v"(tk[0]), [tk1]"+v"(tk[1]), [tk2]"+v"(tk[2]),
              [tk3]"+v"(tk[3]), [tk4]"+v"(tk[4]), [tk5]"+v"(tk[5]),
              [q0]"=&v"(q0), [q1]"=&v"(q1), [q2]"=&v"(q2), [q3]"=&v"(q3),
              [T0]"=&v"(T0), [T1]"=&v"(T1), [T2]"=&v"(T2), [T3]"=&v"(T3),
              [U0]"=&v"(U0), [U1]"=&v"(U1), [U2]"=&v"(U2), [U3]"=&v"(U3)
            : [p0]"v"(p[0]),  [p1]"v"(p[1]),  [p2]"v"(p[2]),  [p3]"v"(p[3]),
              [p4]"v"(p[4]),  [p5]"v"(p[5]),  [p6]"v"(p[6]),  [p7]"v"(p[7]),
              [p8]"v"(p[8]),  [p9]"v"(p[9]),  [p10]"v"(p[10]), [p11]"v"(p[11]),
              [p12]"v"(p[12]), [p13]"v"(p[13]), [p14]"v"(p[14]), [p15]"v"(p[15]));
    };

    auto LD = [&](H8& x1, H8& x2, unsigned& x3, const int s) {
        const unsigned long long a = abase_u + (unsigned long long)s * 2048ull;
        gl4(x1.u4, a);                 // kgroup h
        gl4_1024(x2.u4, a);            // kgroup 2+h  (+1024 B)
        gl1(x3, nbase_u + (unsigned long long)s * 128ull);
    };

    // depth-1 ping-pong, 2 slots (tail load runs <=2KB past the chunk --
    // still inside workspace, unused)
    H8 sA1, sA2, sB1, sB2;
    unsigned nA, nB;
    LD(sA1, sA2, nA, 0);
    for (int s = 0; s < NSUB; s += 2) {
        LD(sB1, sB2, nB, s + 1);
        VMWAIT3; compute(sA1, sA2, nA, s);
        LD(sA1, sA2, nA, s + 2);
        VMWAIT3; compute(sB1, sB2, nB, s + 1);
    }

    // set the h bit (bit 2 of id field) on the 6 survivors, once per chunk
#pragma unroll
    for (int r = 0; r < 6; ++r)
        tk[r] = __uint_as_float(__float_as_uint(tk[r]) | (unsigned)(h << 2));

    // cross-half merge: SNAPSHOT partner's list before mutating
    float other[6];
#pragma unroll
    for (int i = 0; i < 6; ++i) other[i] = __shfl_xor(tk[i], 32, 64);
#pragma unroll
    for (int i = 0; i < 6; ++i) {
        float val = other[i];
#pragma unroll
        for (int j = 0; j < 6; ++j) { float mx = fmaxf(tk[j], val); val = fminf(tk[j], val); tk[j] = mx; }
    }
    if (h == 0) {
        unsigned* dst = cand + ((size_t)q * NC + chunk) * 6;
#pragma unroll
        for (int r = 0; r < 6; ++r) dst[r] = __float_as_uint(tk[r]);
    }
}

// ---------------- kernel 2: global approx top-12, exact rescore, top-5, blend ----------------
__global__ __launch_bounds__(256) void k_merge(const float* __restrict__ Q,
                                               const float* __restrict__ DB,
                                               const float* __restrict__ AUX,
                                               const unsigned* __restrict__ cand,
                                               float* __restrict__ out) {
    const int tid = threadIdx.x, lane = tid & 63, w = tid >> 6;
    const int q = blockIdx.x * 4 + w;

    const unsigned* cq = cand + (size_t)q * NCAND + (size_t)lane * 6;
    float cur[6];
#pragma unroll
    for (int r = 0; r < 6; ++r) cur[r] = __uint_as_float(cq[r]);

    float wv[12]; int wl[12];
#pragma unroll
    for (int r = 0; r < 12; ++r) {
        float bv = cur[0]; int bl = lane;
#pragma unroll
        for (int off = 32; off >= 1; off >>= 1) {
            float ov = __shfl_xor(bv, off, 64);
            int   ol = __shfl_xor(bl, off, 64);
            if (ov > bv || (ov == bv && ol < bl)) { bv = ov; bl = ol; }
        }
        wv[r] = bv; wl[r] = bl;
        if (bl == lane) {
#pragma unroll
            for (int s = 0; s < 5; ++s) cur[s] = cur[s + 1];
            cur[5] = -1.f;
        }
    }

    float dist = 1e30f; int dbi = 0x7fffffff;
    if (lane < 12) {
        unsigned u = __float_as_uint(wv[lane]) & 1023u;   // chunk-local point id
        dbi = wl[lane] * CH + (int)u;
        const float4* dp = (const float4*)(DB + (size_t)dbi * DIM);
        const float4* qp = (const float4*)(Q + (size_t)q * DIM);
        float dot = 0.f, qs = 0.f, ds = 0.f;
#pragma unroll
        for (int j = 0; j < DIM / 4; ++j) {
            float4 a = qp[j], d = dp[j];
            dot += a.x * d.x + a.y * d.y + a.z * d.z + a.w * d.w;
            qs  += a.x * a.x + a.y * a.y + a.z * a.z + a.w * a.w;
            ds  += d.x * d.x + d.y * d.y + d.z * d.z + d.w * d.w;
        }
        dist = sqrtf(fmaxf(qs + ds - 2.f * dot, 0.f));
    }
    float wd[KNN]; int wi[KNN];
#pragma unroll
    for (int r = 0; r < KNN; ++r) {
        float bd = dist; int bi = dbi;
#pragma unroll
        for (int off = 32; off >= 1; off >>= 1) {
            float od = __shfl_xor(bd, off, 64);
            int   oi = __shfl_xor(bi, off, 64);
            if (od < bd || (od == bd && oi < bi)) { bd = od; bi = oi; }
        }
        wd[r] = bd; wi[r] = bi;
        if (dist == bd && dbi == bi) dist = 1e30f;
    }
    float ww[KNN], W = 0.f;
#pragma unroll
    for (int r = 0; r < KNN; ++r) { ww[r] = 1.f / (wd[r] + 1e-6f); W += ww[r]; }
    if (lane < DIM) {
        float o = 0.f;
#pragma unroll
        for (int r = 0; r < KNN; ++r) o += ww[r] * AUX[(size_t)wi[r] * DIM + lane];
        out[(size_t)q * DIM + lane] = o / W;
    }
}

// ---------------- launch ----------------
extern "C" void kernel_launch(void* const* d_in, const int* in_sizes, int n_in,
                              void* d_out, int out_size, void* d_ws, size_t ws_size,
                              hipStream_t stream) {
    const float* Q   = (const float*)d_in[0];
    const float* DB  = (const float*)d_in[1];
    const float* AUX = (const float*)d_in[2];
    float* out = (float*)d_out;

    char* ws = (char*)d_ws;
    uint4*    DBh = (uint4*)ws;                         ws += (size_t)(N_DB / 32) * 128 * 16; // 4 MB
    unsigned* DBn = (unsigned*)ws;                      ws += (size_t)N_DB * 4;               // 256 KB
    unsigned* cand = (unsigned*)ws;                     // 4096*384*4 = 6 MB  (total 10.25 MB)

    k_prep<<<N_DB / 256, 256, 0, stream>>>(DB, DBh, DBn);
    k_scan<<<(N_Q / 128) * NC, 256, 0, stream>>>(Q, DBh, DBn, cand);
    k_merge<<<N_Q / 4, 256, 0, stream>>>(Q, DB, AUX, cand, out);
}